// Round 7
// baseline (310.011 us; speedup 1.0000x reference)
//
#include <hip/hip_runtime.h>

// GCN 2-layer + pool + head, R22: two-level radix partition kills write amplification.
// R21's k_part (55us) wrote 113-130MB for a 25.6MB payload: with 2048 fine buckets a
// block's per-bucket chunk is ~8 edges = ONE 64B line, filled over the whole block
// lifetime -> 2048 slow-filling open lines/block thrash L2. Fix: two passes, each with
// few fast-filling write streams:
//   k_p1: block-major partition into coarse 512-col buckets (<=256 cursors, chunk~64
//         edges=8 lines -> amp ~1x). Computes fine hist in-kernel + feeds bcnt (k_cnt
//         DELETED). Writes bof1 run table.
//   k_scan: fine-bucket exclusive scan -> bstE (with [K]=E sentinel).
//   k_p2: one block per coarse bucket: gather 256 contiguous runs (coalesced), scatter
//         by fine bucket (8 cursors, ballot-aggregated LDS atomics) to GLOBALLY
//         contiguous fine regions at bstE.
//   k_grp: back to R17 contiguous-input form (no run table/seg) -> srt/cptr/dinv/g1b/acc1.
//   k_csr x2, k_mid, k_pool, k_final unchanged. srt aliases dead bp1 (ws ~62MB).
//   h[c] = b + dinv[c]*( g[c] + sum_e w_e * g[row_e] ),  g = dinv * (prev @ W)

#define SH 6                // fine bucket = 64 cols
#define CSH 9               // coarse bucket = 512 cols
#define FPC 8               // fine per coarse
#define RB 64
#define KMAX 2048           // N <= 131072 (row packs in 17 bits)
#define KC_MAX 256
#define KCST (KC_MAX + 1)   // bof1 row stride
#define TPB 256
#define BCAP 8192           // per-bucket LDS capacity in k_grp
#define P1T 1024
#define P2T 1024
#define PB 256              // partition grid

typedef unsigned short ushort_t;
typedef unsigned char u8;
typedef unsigned long long u64;

__device__ __forceinline__ ushort_t f2bf(float v) {
    unsigned u = __float_as_uint(v);
    u += 0x7FFFu + ((u >> 16) & 1u);   // RNE
    return (ushort_t)(u >> 16);
}

__device__ __forceinline__ unsigned quantw(float w) {
    unsigned wq = (unsigned)__float2int_rn(w * 32768.0f);
    return wq > 32767u ? 32767u : wq;
}

// ---------- pass 1: fine hist (-> bcnt) + coarse block-major partition ----------
__global__ __launch_bounds__(P1T)
void k_p1(const int* __restrict__ row, const int* __restrict__ col,
          const float* __restrict__ ew, unsigned* __restrict__ bcnt,
          unsigned* __restrict__ bof1, uint2* __restrict__ bp1,
          int E, int K, int tile) {
    __shared__ unsigned lh[KMAX];                // fine hist (8KB)
    __shared__ unsigned cur[KC_MAX];             // coarse cursors
    __shared__ unsigned wt[KC_MAX / 64];
    int tid = threadIdx.x, b = blockIdx.x;
    int e0 = min(b * tile, E), e1 = min(b * tile + tile, E);
    for (int i = tid; i < KMAX; i += P1T) lh[i] = 0u;
    __syncthreads();
    for (int e = e0 + tid; e < e1; e += P1T) atomicAdd(&lh[col[e] >> SH], 1u);
    __syncthreads();
    for (int i = tid; i < K; i += P1T) {
        unsigned c = lh[i];
        if (c) atomicAdd(&bcnt[i], c);
    }
    // coarse counts = sum of 8 fine; 256-entry exclusive scan (4 waves + wt)
    unsigned cc = 0;
    if (tid < KC_MAX) {
        int f0 = tid * FPC;
#pragma unroll
        for (int q = 0; q < FPC; q++) cc += lh[f0 + q];
    }
    unsigned v = cc;
#pragma unroll
    for (int o = 1; o < 64; o <<= 1) {
        unsigned u = __shfl_up(v, o, 64);
        if ((tid & 63) >= o) v += u;
    }
    if (tid < KC_MAX && (tid & 63) == 63) wt[tid >> 6] = v;
    __syncthreads();
    if (tid == 0) {
        unsigned acc = 0;
#pragma unroll
        for (int w = 0; w < KC_MAX / 64; w++) { unsigned t = wt[w]; wt[w] = acc; acc += t; }
    }
    __syncthreads();
    if (tid < KC_MAX) {
        unsigned ex = wt[tid >> 6] + (v - cc);
        cur[tid] = (unsigned)e0 + ex;
        bof1[(size_t)b * KCST + tid] = (unsigned)e0 + ex;
        if (tid == KC_MAX - 1) bof1[(size_t)b * KCST + KC_MAX] = (unsigned)e0 + ex + cc;
    }
    __syncthreads();
    // scatter by coarse bucket into private block region (col tile L2-hot re-read)
    for (int e = e0 + tid; e < e1; e += P1T) {
        int c = col[e];
        unsigned pos = atomicAdd(&cur[c >> CSH], 1u);
        bp1[pos] = make_uint2((unsigned)row[e] | (quantw(ew[e]) << 17), (unsigned)c);
    }
}

// ---------- exclusive scan over fine counts -> bstE[0..K] (sentinel [K]=E) ----------
__global__ void k_scan(const unsigned* __restrict__ cnt, unsigned* __restrict__ start,
                       int K) {
    __shared__ unsigned a[KMAX], b[KMAX];
    int t = threadIdx.x;  // 1024
    for (int i = t; i < KMAX; i += 1024) a[i] = (i < K) ? cnt[i] : 0u;
    __syncthreads();
    unsigned *src = a, *dst = b;
    for (int off = 1; off < KMAX; off <<= 1) {
        for (int i = t; i < KMAX; i += 1024)
            dst[i] = (i >= off) ? src[i] + src[i - off] : src[i];
        __syncthreads();
        unsigned* tmp = src; src = dst; dst = tmp;
    }
    for (int i = t; i <= K; i += 1024) start[i] = (i == 0) ? 0u : src[i - 1];
}

// ---------- pass 2: coarse runs -> globally-contiguous fine buckets ----------
__global__ __launch_bounds__(P2T)
void k_p2(const uint2* __restrict__ bp1, const unsigned* __restrict__ bof1,
          const unsigned* __restrict__ bstE, unsigned* __restrict__ brp,
          u8* __restrict__ bcl, int E, int K) {
    __shared__ unsigned rsrc[PB], rlen[PB];
    __shared__ unsigned lcur[FPC];
    int tid = threadIdx.x, C = blockIdx.x;
    int lane = tid & 63, wv = tid >> 6;
    if (tid < PB) {
        unsigned s0 = bof1[(size_t)tid * KCST + C];
        unsigned s1 = bof1[(size_t)tid * KCST + C + 1];
        rsrc[tid] = s0; rlen[tid] = s1 - s0;
    }
    if (tid < FPC) {
        int kf = C * FPC + tid;
        lcur[tid] = (kf <= K) ? bstE[kf] : (unsigned)E;
    }
    __syncthreads();
    for (int r = wv; r < PB; r += P2T / 64) {       // run-per-wave, coalesced reads
        unsigned s0 = rsrc[r], L = rlen[r];
        for (unsigned i0 = 0; i0 < L; i0 += 64) {
            unsigned i = i0 + (unsigned)lane;
            bool valid = i < L;
            uint2 p = valid ? bp1[s0 + i] : make_uint2(0u, 0u);
            unsigned j = (p.y >> SH) & (FPC - 1);
            unsigned pos = 0u;
#pragma unroll
            for (int J = 0; J < FPC; ++J) {          // ballot-aggregated cursor bump
                u64 m = __ballot(valid && j == (unsigned)J);
                if (valid && j == (unsigned)J) {
                    int leader = __ffsll(m) - 1;
                    unsigned base = 0u;
                    if (lane == leader) base = atomicAdd(&lcur[J], (unsigned)__popcll(m));
                    base = __shfl(base, leader, 64);
                    pos = base + (unsigned)__popcll(m & ((1ULL << lane) - 1ULL));
                }
            }
            if (valid) { brp[pos] = p.x; bcl[pos] = (u8)(p.y & 63u); }
        }
    }
}

// ---------- per-bucket (contiguous input): group-by-col -> srt + cptr + dinv + g1/acc1 ----
__global__ __launch_bounds__(TPB)
void k_grp(const unsigned* __restrict__ brp, const u8* __restrict__ bcl,
           const unsigned* __restrict__ bstE, const float* __restrict__ x,
           const float* __restrict__ W1, unsigned* __restrict__ srt,
           unsigned* __restrict__ cptr, float* __restrict__ dinv,
           unsigned* __restrict__ g1b, float* __restrict__ acc1,
           int N, int E, int K) {
    // bijective XCD-contiguous swizzle (m204): consecutive buckets share an XCD's L2
    int orig = blockIdx.x;
    int q8 = K >> 3, r8 = K & 7;
    int xcd = orig & 7, idx = orig >> 3;
    int k = (xcd < r8 ? xcd * (q8 + 1) : r8 * (q8 + 1) + (xcd - r8) * q8) + idx;
    int node0 = k << SH;

    __shared__ unsigned ebuf[BCAP];          // 32KB (reused as gtmp after scatter)
    __shared__ u8 cbuf[BCAP];                // 8KB
    __shared__ unsigned cnt64[RB], st64[RB], dq[RB];
    __shared__ float dl[RB], lx[RB * 3], lw[48];
    int tid = threadIdx.x;
    unsigned s = bstE[k], c = bstE[k + 1] - s;
    if (tid < RB) { cnt64[tid] = 0u; dq[tid] = 0u; }
    if (tid < 48) lw[tid] = W1[tid];
    int nn = min(RB, N - node0);
    for (int i = tid; i < nn * 3; i += TPB) lx[i] = x[(size_t)node0 * 3 + i];
    __syncthreads();

    bool fits = (c <= (unsigned)BCAP);
    if (fits) {
        for (unsigned j = tid; j < c; j += TPB) {
            unsigned p = brp[s + j];
            unsigned cl = bcl[s + j];
            ebuf[j] = p; cbuf[j] = (u8)cl;
            atomicAdd(&cnt64[cl], 1u);
            atomicAdd(&dq[cl], p >> 17);
        }
        __syncthreads();
        if (tid == 0) {                                  // tiny serial scan of 64
            unsigned acc = 0;
            for (int i = 0; i < RB; i++) { st64[i] = acc; acc += cnt64[i]; cnt64[i] = 0u; }
        }
        __syncthreads();
        for (unsigned j = tid; j < c; j += TPB) {
            unsigned cl = cbuf[j];
            unsigned pos = st64[cl] + atomicAdd(&cnt64[cl], 1u);
            srt[s + pos] = ebuf[j];                      // within-bucket contiguous range
        }
    } else {                                             // 2-pass fallback (rare)
        for (unsigned j = tid; j < c; j += TPB) {
            unsigned cl = bcl[s + j];
            atomicAdd(&cnt64[cl], 1u);
            atomicAdd(&dq[cl], brp[s + j] >> 17);
        }
        __syncthreads();
        if (tid == 0) {
            unsigned acc = 0;
            for (int i = 0; i < RB; i++) { st64[i] = acc; acc += cnt64[i]; cnt64[i] = 0u; }
        }
        __syncthreads();
        for (unsigned j = tid; j < c; j += TPB) {
            unsigned cl = bcl[s + j];
            unsigned pos = st64[cl] + atomicAdd(&cnt64[cl], 1u);
            srt[s + pos] = brp[s + j];
        }
    }
    __syncthreads();
    if (tid < RB) {
        float d = rsqrtf(1.0f + (float)dq[tid] * (1.0f / 32768.0f));  // self-loop +1
        dl[tid] = d;
        if (tid < nn) {
            dinv[node0 + tid] = d;
            cptr[node0 + tid] = s + st64[tid];
        }
    }
    if (tid == 0 && node0 + nn == N) cptr[N] = (unsigned)E;  // sentinel
    __syncthreads();
    float* gtmp = (float*)ebuf;   // safe: all ebuf reads complete
    for (int idx2 = tid; idx2 < nn * 16; idx2 += TPB) {
        int n = idx2 >> 4, f = idx2 & 15;
        float vv = dl[n] * (lx[n * 3] * lw[f] + lx[n * 3 + 1] * lw[16 + f] +
                            lx[n * 3 + 2] * lw[32 + f]);
        acc1[(size_t)(node0 + n) * 16 + f] = vv;
        gtmp[idx2] = vv;
    }
    __syncthreads();
    for (int idx2 = tid; idx2 < nn * 8; idx2 += TPB) {
        int n = idx2 >> 3, qq = idx2 & 7;
        g1b[(size_t)(node0 + n) * 8 + qq] =
            (unsigned)f2bf(gtmp[n * 16 + 2 * qq]) |
            ((unsigned)f2bf(gtmp[n * 16 + 2 * qq + 1]) << 16);
    }
}

// ---------- consumer: 8 lanes/col, serial register accumulate, no barriers ----------
__global__ __launch_bounds__(TPB)
void k_csr(const unsigned* __restrict__ srt, const unsigned* __restrict__ cptr,
           const unsigned* __restrict__ gb, float* __restrict__ acc, int N) {
    int t = blockIdx.x * TPB + threadIdx.x;
    int c = t >> 3, f2 = t & 7;
    if (c >= N) return;
    unsigned e = cptr[c], end = cptr[c + 1];
    float a = 0.0f, b = 0.0f;
#pragma unroll 4
    for (; e < end; ++e) {
        unsigned m = srt[e];                         // same addr across 8 lanes -> merged
        float w = (float)(m >> 17) * (1.0f / 32768.0f);
        unsigned u = gb[(size_t)(m & 0x1FFFFu) * 8 + f2];  // bf16x2, L2-resident table
        a = fmaf(w, __uint_as_float(u << 16), a);
        b = fmaf(w, __uint_as_float(u & 0xFFFF0000u), b);
    }
    float2* p = (float2*)&acc[(size_t)c * 16 + 2 * f2];
    float2 v = *p;                                   // exclusive owner: plain RMW
    v.x += a; v.y += b;
    *p = v;
}

// ---------- mid: h1 = relu(b1 + dinv*acc1); g2 = dinv*(h1@W2) -> bf16 + acc2 seed ----------
__global__ void k_mid(const float* __restrict__ acc1, const float* __restrict__ dinv,
                      const float* __restrict__ b1, const float* __restrict__ W2,
                      unsigned* __restrict__ g2b, float* __restrict__ acc2, int N) {
    __shared__ float t[16][16];
    __shared__ float go[16][16];
    __shared__ float w2[256];
    int tid = threadIdx.x;
    int il = tid >> 4, f = tid & 15;
    int i = blockIdx.x * 16 + il;
    w2[tid] = W2[tid];
    float v = 0.0f, d = 0.0f;
    if (i < N) {
        d = dinv[i];
        v = b1[f] + d * acc1[(size_t)i * 16 + f];
        v = v > 0.0f ? v : 0.0f;
    }
    t[il][f] = v;
    __syncthreads();
    float r = 0.0f;
    if (i < N) {
        float o = 0.0f;
#pragma unroll
        for (int kk = 0; kk < 16; kk++) o += t[il][kk] * w2[kk * 16 + f];
        r = d * o;
        acc2[(size_t)i * 16 + f] = r;
    }
    go[il][f] = r;
    __syncthreads();
    if (tid < 128) {
        int il2 = tid >> 3, q = tid & 7;
        int i2 = blockIdx.x * 16 + il2;
        if (i2 < N)
            g2b[(size_t)i2 * 8 + q] = (unsigned)f2bf(go[il2][2 * q]) |
                                      ((unsigned)f2bf(go[il2][2 * q + 1]) << 16);
    }
}

// ---------- pool: h2 = relu(b2 + dinv*acc2) folded into sorted-batch pool ----------
#define PC 1024
__global__ void k_pool(const float* __restrict__ acc2, const float* __restrict__ dinv,
                       const float* __restrict__ b2, const int* __restrict__ batch,
                       float* __restrict__ pooled, int N, int G) {
    int b0 = blockIdx.x * PC;
    int nodes = min(PC, N - b0);
    __shared__ float lacc[64 * 16];
    __shared__ int lbat[PC];
    int tid = threadIdx.x;  // 256
    for (int i = tid; i < nodes; i += 256) lbat[i] = batch[b0 + i];
    __syncthreads();
    int gmin = lbat[0], gmax = lbat[nodes - 1];
    bool fits = (gmax - gmin < 64);
    if (fits) {
        for (int i = tid; i < 64 * 16; i += 256) lacc[i] = 0.0f;
        __syncthreads();
    }
    for (int idx = tid; idx < nodes * 16; idx += 256) {
        int i = idx >> 4, f = idx & 15;
        int n = b0 + i;
        float d = dinv[n];
        float v = b2[f] + d * acc2[(size_t)n * 16 + f];
        v = v > 0.0f ? v : 0.0f;
        if (fits) atomicAdd(&lacc[(lbat[i] - gmin) * 16 + f], v);
        else      atomicAdd(&pooled[lbat[i] * 16 + f], v);
    }
    if (fits) {
        __syncthreads();
        for (int idx = tid; idx < 64 * 16; idx += 256) {
            int g = gmin + (idx >> 4);
            float v = lacc[idx];
            if (g < G && v != 0.0f) atomicAdd(&pooled[g * 16 + (idx & 15)], v);
        }
    }
}

__global__ void k_final(const float* __restrict__ pooled, const float* __restrict__ Wlin,
                        const float* __restrict__ blin, float* __restrict__ out, int G) {
    int t = blockIdx.x * blockDim.x + threadIdx.x;
    int g = t / 7, j = t % 7;
    if (g >= G) return;
    float v = blin[j];
#pragma unroll
    for (int f = 0; f < 16; f++) v += pooled[g * 16 + f] * Wlin[f * 7 + j];
    out[g * 7 + j] = v;
}

static inline int cdiv_i(long long a, long long b) { return (int)((a + b - 1) / b); }

extern "C" void kernel_launch(void* const* d_in, const int* in_sizes, int n_in,
                              void* d_out, int out_size, void* d_ws, size_t ws_size,
                              hipStream_t stream) {
    const float* x     = (const float*)d_in[0];
    const int*   ei    = (const int*)d_in[1];
    const float* ew    = (const float*)d_in[2];
    const int*   batch = (const int*)d_in[3];
    const float* W1    = (const float*)d_in[4];
    const float* b1    = (const float*)d_in[5];
    const float* W2    = (const float*)d_in[6];
    const float* b2    = (const float*)d_in[7];
    const float* Wlin  = (const float*)d_in[8];
    const float* blin  = (const float*)d_in[9];
    float* out = (float*)d_out;

    const int N = in_sizes[0] / 3;
    const int E = in_sizes[2];
    const int G = out_size / 7;
    const int K = (N + RB - 1) >> SH;            // fine buckets (1563)
    const int KC = cdiv_i(N, 1 << CSH);          // coarse buckets (196)
    const int tile = cdiv_i(E, PB);
    const int* row = ei;
    const int* col = ei + E;

    // layout: bp1(uint2,E) [srt aliases bp1: dead after k_p2] | brp | bcl | cptr | dinv
    //       | g1b | g2b | acc1 | acc2 | bstE | bof1 | [zero: bcnt | pooled]
    uint2*    bp1    = (uint2*)d_ws;                        // E (8B)
    unsigned* srt    = (unsigned*)d_ws;                     // E (aliases bp1)
    unsigned* brp    = (unsigned*)(bp1 + E);                // E
    u8*       bcl    = (u8*)(brp + E);                      // E (E%4==0)
    unsigned* cptr   = (unsigned*)(bcl + E);                // N+1
    float*    dinv   = (float*)(cptr + N + 1);              // N
    unsigned* g1b    = (unsigned*)(dinv + N);               // N*8 (bf16 x16)
    unsigned* g2b    = g1b + (size_t)N * 8;                 // N*8
    float*    acc1   = (float*)(g2b + (size_t)N * 8);       // N*16
    float*    acc2   = acc1 + (size_t)N * 16;               // N*16
    unsigned* bstE   = (unsigned*)(acc2 + (size_t)N * 16);  // KMAX+1
    unsigned* bof1   = bstE + (KMAX + 1);                   // PB*KCST
    unsigned* bcnt   = bof1 + (size_t)PB * KCST;            // KMAX
    float*    pooled = (float*)(bcnt + KMAX);               // G*16

    hipMemsetAsync(bcnt, 0, (KMAX + (size_t)G * 16) * sizeof(unsigned), stream);

    // CSR build: coarse partition(+fine hist) -> fine scan -> fine partition -> group
    k_p1<<<PB, P1T, 0, stream>>>(row, col, ew, bcnt, bof1, bp1, E, K, tile);
    k_scan<<<1, 1024, 0, stream>>>(bcnt, bstE, K);
    k_p2<<<KC, P2T, 0, stream>>>(bp1, bof1, bstE, brp, bcl, E, K);
    k_grp<<<K, TPB, 0, stream>>>(brp, bcl, bstE, x, W1, srt, cptr, dinv, g1b, acc1,
                                 N, E, K);

    // layer 1: barrier-free CSR gather/reduce
    k_csr<<<cdiv_i((long long)N * 8, TPB), TPB, 0, stream>>>(srt, cptr, g1b, acc1, N);

    // mid: h1 -> g2(bf16) + acc2 seed
    k_mid<<<cdiv_i(N, 16), TPB, 0, stream>>>(acc1, dinv, b1, W2, g2b, acc2, N);

    // layer 2
    k_csr<<<cdiv_i((long long)N * 8, TPB), TPB, 0, stream>>>(srt, cptr, g2b, acc2, N);

    // pool + head
    k_pool<<<cdiv_i(N, PC), TPB, 0, stream>>>(acc2, dinv, b2, batch, pooled, N, G);
    k_final<<<cdiv_i((long long)G * 7, TPB), TPB, 0, stream>>>(pooled, Wlin, blin, out, G);
}